// Round 10
// baseline (258.552 us; speedup 1.0000x reference)
//
#include <hip/hip_runtime.h>
#include <hip/hip_bf16.h>
#include <stdint.h>

#define BB 4
#define TSEQ 512
#define NSEQ 512
#define DD 1024
#define EE 1024
#define HH 16
#define HD 64

typedef __attribute__((ext_vector_type(8))) short bf16x8;
typedef __attribute__((ext_vector_type(4))) float f32x4;

__device__ __forceinline__ unsigned short f2bf(float f) {
    union { float f; uint32_t u; } v; v.f = f;
    uint32_t u = v.u;
    uint32_t r = (u + 0x7fffu + ((u >> 16) & 1u)) >> 16;
    return (unsigned short)r;
}

__device__ __forceinline__ uint32_t pkbf(float a, float b) {
    __hip_bfloat162 t = __float22bfloat162_rn(float2{a, b});
    return *(uint32_t*)&t;
}

#define GLD16(gp, lp)                                                          \
    __builtin_amdgcn_global_load_lds(                                          \
        (const __attribute__((address_space(1))) unsigned int*)(gp),           \
        (__attribute__((address_space(3))) unsigned int*)(lp), 16, 0, 0)

// ---------------------------------------------------------------------------
// K1a: fused weight transpose+cvt for all 4 weight tensors
// ---------------------------------------------------------------------------
__global__ __launch_bounds__(256) void tw_all_kernel(
    const float* __restrict__ q_w, const float* __restrict__ k_w,
    const float* __restrict__ v_w, const float* __restrict__ out_w,
    unsigned short* __restrict__ qwt, unsigned short* __restrict__ kwt,
    unsigned short* __restrict__ vwt, unsigned short* __restrict__ owt)
{
    __shared__ __align__(16) unsigned short Ts[64 * 72];
    int k0 = blockIdx.x * 64, n0 = blockIdx.y * 64;
    int z = blockIdx.z;
    const float* in; unsigned short* out;
    if (z < 3)       { in = q_w + (size_t)z * DD * DD;         out = qwt + (size_t)z * DD * DD; }
    else if (z == 3) { in = k_w;                               out = kwt; }
    else if (z == 4) { in = v_w;                               out = vwt; }
    else             { in = out_w + (size_t)(z - 5) * DD * DD; out = owt + (size_t)(z - 5) * DD * DD; }
    int tid = threadIdx.x;
    int r = tid >> 2, c0 = (tid & 3) * 16;
#pragma unroll
    for (int i = 0; i < 4; i++) {
        float4 v = *(const float4*)(in + (size_t)(k0 + r) * DD + n0 + c0 + i * 4);
        Ts[(c0 + i * 4 + 0) * 72 + r] = f2bf(v.x);
        Ts[(c0 + i * 4 + 1) * 72 + r] = f2bf(v.y);
        Ts[(c0 + i * 4 + 2) * 72 + r] = f2bf(v.z);
        Ts[(c0 + i * 4 + 3) * 72 + r] = f2bf(v.w);
    }
    __syncthreads();
#pragma unroll
    for (int i = 0; i < 2; i++) {
        int idx = i * 256 + tid;
        int row = idx >> 3, ko = (idx & 7) * 8;
        *(uint4*)(out + (size_t)(n0 + row) * DD + k0 + ko) =
            *(const uint4*)(Ts + row * 72 + ko);
    }
}

// ---------------------------------------------------------------------------
// K1b: adaln. grid (64 col-chunks of 32, 4 branches), block 256.
// ---------------------------------------------------------------------------
__global__ __launch_bounds__(256) void adaln_kernel(
    const float* __restrict__ emb,
    const float* __restrict__ adaln_w, const float* __restrict__ adaln_b,
    const float* __restrict__ xf_w, const float* __restrict__ xf_b,
    float* __restrict__ scaleB, float* __restrict__ shiftB)
{
    __shared__ __align__(16) float seT[EE][4];
    __shared__ float buf[128 * 33];
    int tid = threadIdx.x;
    int chunk = blockIdx.x, j = blockIdx.y;
#pragma unroll
    for (int b = 0; b < 4; b++) {
        float4 e4 = ((const float4*)(emb + (size_t)b * EE))[tid];
        seT[tid * 4 + 0][b] = e4.x / (1.f + __expf(-e4.x));
        seT[tid * 4 + 1][b] = e4.y / (1.f + __expf(-e4.y));
        seT[tid * 4 + 2][b] = e4.z / (1.f + __expf(-e4.z));
        seT[tid * 4 + 3][b] = e4.w / (1.f + __expf(-e4.w));
    }
    __syncthreads();
    const float* W    = (j < 3) ? (adaln_w + (size_t)j * EE * 2 * DD) : xf_w;
    const float* bias = (j < 3) ? (adaln_b + (size_t)j * 2 * DD) : xf_b;
    int eg = tid >> 3, cg = tid & 7;
    int c0 = chunk * 32 + cg * 4;
    const float* Wp = W + (size_t)(eg * 32) * (2 * DD) + c0;
    float4 a0 = {0,0,0,0}, a1 = {0,0,0,0}, a2 = {0,0,0,0}, a3 = {0,0,0,0};
#pragma unroll 8
    for (int e = 0; e < 32; e++) {
        float4 w = *(const float4*)(Wp + (size_t)e * (2 * DD));
        float4 s = *(const float4*)&seT[eg * 32 + e][0];
        a0.x += s.x * w.x; a0.y += s.x * w.y; a0.z += s.x * w.z; a0.w += s.x * w.w;
        a1.x += s.y * w.x; a1.y += s.y * w.y; a1.z += s.y * w.z; a1.w += s.y * w.w;
        a2.x += s.z * w.x; a2.y += s.z * w.y; a2.z += s.z * w.z; a2.w += s.z * w.w;
        a3.x += s.w * w.x; a3.y += s.w * w.y; a3.z += s.w * w.z; a3.w += s.w * w.w;
    }
    float accs[4][4] = {{a0.x,a0.y,a0.z,a0.w},{a1.x,a1.y,a1.z,a1.w},
                        {a2.x,a2.y,a2.z,a2.w},{a3.x,a3.y,a3.z,a3.w}};
#pragma unroll
    for (int b = 0; b < 4; b++)
#pragma unroll
        for (int i = 0; i < 4; i++)
            buf[(b * 32 + cg * 4 + i) * 33 + eg] = accs[b][i];
    __syncthreads();
    if (tid < 128) {
        int b = tid >> 5, cl = tid & 31;
        float s = 0.f;
#pragma unroll 8
        for (int e = 0; e < 32; e++) s += buf[(b * 32 + cl) * 33 + e];
        int c = chunk * 32 + cl;
        float v = s + bias[c];
        if (c < DD) scaleB[(size_t)(j * 4 + b) * DD + c] = v;
        else        shiftB[(size_t)(j * 4 + b) * DD + (c - DD)] = v;
    }
}

// ---------------------------------------------------------------------------
// K2: LayerNorm + modulate, cast bf16
// ---------------------------------------------------------------------------
__global__ __launch_bounds__(256) void ln_mod_kernel(
    const float* __restrict__ x1, const float* __restrict__ x2,
    const float* __restrict__ x3, const float* __restrict__ xf,
    const float* __restrict__ scaleB, const float* __restrict__ shiftB,
    unsigned short* __restrict__ hq, unsigned short* __restrict__ hx)
{
    __shared__ float rs[4], rq[4];
    int row = blockIdx.x, tid = threadIdx.x;
    const float* src; unsigned short* dst; int sb;
    if (row < 6144) {
        int b = row / 1536, t3 = row % 1536;
        int br = t3 >> 9, t = t3 & 511;
        const float* xs = (br == 0) ? x1 : ((br == 1) ? x2 : x3);
        src = xs + ((size_t)b * TSEQ + t) * DD;
        dst = hq + (size_t)row * DD;
        sb = br * 4 + b;
    } else {
        int idx = row - 6144;
        src = xf + (size_t)idx * DD;
        dst = hx + (size_t)idx * DD;
        sb = 12 + (idx >> 9);
    }
    float4 x = ((const float4*)src)[tid];
    float s = x.x + x.y + x.z + x.w;
    float q = x.x * x.x + x.y * x.y + x.z * x.z + x.w * x.w;
    for (int o = 1; o < 64; o <<= 1) { s += __shfl_xor(s, o, 64); q += __shfl_xor(q, o, 64); }
    int lane = tid & 63, wid = tid >> 6;
    if (lane == 0) { rs[wid] = s; rq[wid] = q; }
    __syncthreads();
    float S = rs[0] + rs[1] + rs[2] + rs[3];
    float Q = rq[0] + rq[1] + rq[2] + rq[3];
    float mu = S * (1.f / DD);
    float var = Q * (1.f / DD) - mu * mu;
    float rstd = rsqrtf(var + 1e-6f);
    float4 sc = ((const float4*)(scaleB + (size_t)sb * DD))[tid];
    float4 sh = ((const float4*)(shiftB + (size_t)sb * DD))[tid];
    ushort4 o;
    o.x = f2bf((x.x - mu) * rstd * (1.f + sc.x) + sh.x);
    o.y = f2bf((x.y - mu) * rstd * (1.f + sc.y) + sh.y);
    o.z = f2bf((x.z - mu) * rstd * (1.f + sc.z) + sh.z);
    o.w = f2bf((x.w - mu) * rstd * (1.f + sc.w) + sh.w);
    ((ushort4*)dst)[tid] = o;
}

// ---------------------------------------------------------------------------
// GEMM core: 128x64 tile, BK=64, conflict-free XOR swizzle, 4 waves 2x2.
// (R2-verified best config; all later restructures were neutral or worse.)
// ---------------------------------------------------------------------------
__device__ __forceinline__ void gemm_core64(
    const unsigned short* __restrict__ A, const unsigned short* __restrict__ W,
    int m0, int n0, unsigned short* As, unsigned short* Bs,
    int tid, f32x4 acc[4][2])
{
    int lane = tid & 63, wid = tid >> 6;
    int fm = lane & 15, quad = lane >> 4;
    int wm = wid >> 1, wn = wid & 1;
    int sr = tid >> 3;                    // row 0..31
    int sc = tid & 7;                     // LDS chunk position 0..7
    int gko = (sc ^ (sr & 7)) * 8;        // global k-chunk landing at pos sc
    const unsigned short* Ap = A + (size_t)(m0 + sr) * DD + gko;
    const unsigned short* Wp = W + (size_t)(n0 + sr) * DD + gko;
    unsigned short* la = As + tid * 8;    // = sr*64 + sc*8
    unsigned short* lb = Bs + tid * 8;
    int f7 = fm & 7;
    for (int k0 = 0; k0 < DD; k0 += 64) {
#pragma unroll
        for (int i = 0; i < 4; i++)
            GLD16(Ap + (size_t)(32 * i) * DD + k0, la + i * 2048);
#pragma unroll
        for (int i = 0; i < 2; i++)
            GLD16(Wp + (size_t)(32 * i) * DD + k0, lb + i * 2048);
        __syncthreads();
#pragma unroll
        for (int kh = 0; kh < 2; kh++) {
            int sq = ((quad + 4 * kh) ^ f7) * 8;
            bf16x8 af[4], bfr[2];
#pragma unroll
            for (int mt = 0; mt < 4; mt++)
                af[mt] = *(const bf16x8*)(As + (wm * 64 + mt * 16 + fm) * 64 + sq);
#pragma unroll
            for (int nt = 0; nt < 2; nt++)
                bfr[nt] = *(const bf16x8*)(Bs + (wn * 32 + nt * 16 + fm) * 64 + sq);
#pragma unroll
            for (int mt = 0; mt < 4; mt++)
#pragma unroll
                for (int nt = 0; nt < 2; nt++)
                    acc[mt][nt] = __builtin_amdgcn_mfma_f32_16x16x32_bf16(af[mt], bfr[nt], acc[mt][nt], 0, 0, 0);
        }
        __syncthreads();
    }
}

// ---------------------------------------------------------------------------
// K3: fused Q/K/V projection -> MFMA-fragment-packed outputs.
// flat grid 1280, PRODUCER XCD PAIRING: id%16 = n-tile (head), id/16 = ty.
// XCD heuristic (id%8) => head h's Q/K/V all written by XCD h%8, matching
// attn's consumer mapping below (cross-XCD reads -> local-L2 reads).
// ---------------------------------------------------------------------------
__global__ __launch_bounds__(256) void qkv_gemm(
    const unsigned short* __restrict__ hq, const unsigned short* __restrict__ hx,
    const unsigned short* __restrict__ qwt, const unsigned short* __restrict__ kwt,
    const unsigned short* __restrict__ vwt,
    const float* __restrict__ q_b, const float* __restrict__ k_b,
    const float* __restrict__ v_b,
    unsigned short* __restrict__ Qpk, unsigned short* __restrict__ Kpk,
    unsigned short* __restrict__ Vpk)
{
    __shared__ __align__(16) unsigned short As[128 * 64];
    __shared__ __align__(16) unsigned short Bs[64 * 64];
    int id = blockIdx.x;
    int ty = id / 16, n0 = (id % 16) * 64;
    const unsigned short *A, *W; const float* bias; int mode, m0;
    if (ty < 48) {
        m0 = ty * 128;
        int br = (m0 % 1536) >> 9;
        A = hq; W = qwt + (size_t)br * DD * DD; bias = q_b + (size_t)br * DD; mode = 0;
    } else if (ty < 64) {
        m0 = (ty - 48) * 128; A = hx; W = kwt; bias = k_b; mode = 1;
    } else {
        m0 = (ty - 64) * 128; A = hx; W = vwt; bias = v_b; mode = 2;
    }
    int tid = threadIdx.x, lane = tid & 63, wid = tid >> 6;
    int fm = lane & 15, quad = lane >> 4;
    int wm = wid >> 1, wn = wid & 1;
    f32x4 z = {0.f, 0.f, 0.f, 0.f};
    f32x4 acc[4][2];
#pragma unroll
    for (int mt = 0; mt < 4; mt++)
#pragma unroll
        for (int nt = 0; nt < 2; nt++) acc[mt][nt] = z;
    gemm_core64(A, W, m0, n0, As, Bs, tid, acc);
#pragma unroll
    for (int mt = 0; mt < 4; mt++) {
#pragma unroll
        for (int nt = 0; nt < 2; nt++) {
            int c = n0 + wn * 32 + nt * 16 + fm;
            float bv = bias[c];
            int r0 = m0 + wm * 64 + mt * 16 + quad * 4;
            int h = c >> 6;
            if (mode == 0) {
                int b = r0 / 1536, t3 = r0 % 1536;
                int kk = (c >> 5) & 1, o = c & 31;
                size_t base = ((((size_t)(b * HH + h) * 2 + kk) * 1536) + t3) * 32 + o;
#pragma unroll
                for (int reg = 0; reg < 4; reg++)
                    Qpk[base + (size_t)reg * 32] = f2bf((acc[mt][nt][reg] + bv) * 0.125f);
            } else if (mode == 1) {
                int b = r0 >> 9, n = r0 & 511;
                int kk = (c >> 5) & 1, o = c & 31;
                size_t base = ((((size_t)(b * HH + h) * 2 + kk) * 512) + n) * 32 + o;
#pragma unroll
                for (int reg = 0; reg < 4; reg++)
                    Kpk[base + (size_t)reg * 32] = f2bf(acc[mt][nt][reg] + bv);
            } else {
                int b = r0 >> 9, n = r0 & 511;
                int hd = c & 63, cv = n >> 5, ko = n & 31;
                ushort4 st;
                st.x = f2bf(acc[mt][nt][0] + bv);
                st.y = f2bf(acc[mt][nt][1] + bv);
                st.z = f2bf(acc[mt][nt][2] + bv);
                st.w = f2bf(acc[mt][nt][3] + bv);
                *(ushort4*)(Vpk + ((((size_t)(b * HH + h) * 16 + cv) * 64) + hd) * 32 + ko) = st;
            }
        }
    }
}

// ---------------------------------------------------------------------------
// K5: out projection, fp32 out remapped branch-major. flat grid 768:
// m = id % 48 (XCD-affine), n-tile(64) = id / 48.
// ---------------------------------------------------------------------------
__global__ __launch_bounds__(256) void out_gemm(
    const unsigned short* __restrict__ Ain, const unsigned short* __restrict__ owt,
    const float* __restrict__ out_b, float* __restrict__ outp)
{
    __shared__ __align__(16) unsigned short As[128 * 64];
    __shared__ __align__(16) unsigned short Bs[64 * 64];
    int id = blockIdx.x;
    int m0 = (id % 48) * 128, n0 = (id / 48) * 64;
    int br = (m0 % 1536) >> 9;
    const unsigned short* W = owt + (size_t)br * DD * DD;
    const float* bias = out_b + (size_t)br * DD;
    int tid = threadIdx.x, lane = tid & 63, wid = tid >> 6;
    int fm = lane & 15, quad = lane >> 4;
    int wm = wid >> 1, wn = wid & 1;
    f32x4 z = {0.f, 0.f, 0.f, 0.f};
    f32x4 acc[4][2];
#pragma unroll
    for (int mt = 0; mt < 4; mt++)
#pragma unroll
        for (int nt = 0; nt < 2; nt++) acc[mt][nt] = z;
    gemm_core64(Ain, W, m0, n0, As, Bs, tid, acc);
#pragma unroll
    for (int mt = 0; mt < 4; mt++) {
#pragma unroll
        for (int nt = 0; nt < 2; nt++) {
            int c = n0 + wn * 32 + nt * 16 + fm;
            float bv = bias[c];
            int r0 = m0 + wm * 64 + mt * 16 + quad * 4;
            int b = r0 / 1536, t3 = r0 % 1536, t = t3 & 511;
#pragma unroll
            for (int reg = 0; reg < 4; reg++)
                outp[(size_t)br * (BB * TSEQ * DD) + (size_t)b * (TSEQ * DD)
                     + (size_t)(t + reg) * DD + c] = acc[mt][nt][reg] + bv;
        }
    }
}

// ---------------------------------------------------------------------------
// K4: attention, 48 queries/block, CONSUMER XCD PAIRING: XCD x owns heads
// {x, x+8} (matching qkv's producer mapping) -> per-XCD working set 2.6MB
// fits the 4MB local L2; Q/K/V reads become local-L2 where still resident.
// Per XCD: 8 (b,h) pairs x 32 m-tiles = 256 blocks; consecutive blocks share
// a head (K/V temporal locality). Grid 2048. T14 V-prefetch retained.
// ---------------------------------------------------------------------------
__global__ __launch_bounds__(256, 3) void attn_kernel(
    const unsigned short* __restrict__ Qpk,
    const unsigned short* __restrict__ Kpk,
    const unsigned short* __restrict__ Vpk,
    const unsigned char* __restrict__ mask,
    unsigned short* __restrict__ attn)
{
    __shared__ __align__(16) unsigned short P[48 * 520];
    __shared__ float redsum[4 * 48];
    int orig = blockIdx.x;
    int xcd = orig & 7;
    int j = orig >> 3;            // 0..255 within XCD
    int u = j >> 5;               // 0..7: (b, h-half)
    int b = u >> 1, h = xcd + (u & 1) * 8;
    int bh = b * 16 + h;
    int m0 = (j & 31) * 48;
    int tid = threadIdx.x, lane = tid & 63, w = tid >> 6;
    int fm = lane & 15, quad = lane >> 4;

    const unsigned char* mp = mask + (size_t)b * NSEQ + w * 128;
    unsigned long long mw0 = __ballot(mp[lane] != 0);
    unsigned long long mw1 = __ballot(mp[64 + lane] != 0);

    // phase 1: S^T = K (Q/8)^T for 48 queries, mask as C-init
    f32x4 acc[8][3];
#pragma unroll
    for (int mt = 0; mt < 8; mt++) {
        unsigned long long word = (mt >= 4) ? mw1 : mw0;
        int kb = (mt * 16 + quad * 4) & 63;
        f32x4 ini;
#pragma unroll
        for (int reg = 0; reg < 4; reg++)
            ini[reg] = ((word >> (kb + reg)) & 1ull) ? -1e30f : 0.f;
        acc[mt][0] = ini; acc[mt][1] = ini; acc[mt][2] = ini;
    }
    const unsigned short* Kbase = Kpk + (size_t)bh * 2 * 512 * 32 + quad * 8;
    const unsigned short* Qbase = Qpk + (size_t)bh * 2 * 1536 * 32 + quad * 8;
    const unsigned short* Vbase = Vpk + (size_t)bh * 16 * 64 * 32 + (size_t)(w * 16 + fm) * 32 + quad * 8;
#pragma unroll
    for (int kk = 0; kk < 2; kk++) {
        bf16x8 bq0 = *(const bf16x8*)(Qbase + (size_t)(kk * 1536 + m0 + fm) * 32);
        bf16x8 bq1 = *(const bf16x8*)(Qbase + (size_t)(kk * 1536 + m0 + 16 + fm) * 32);
        bf16x8 bq2 = *(const bf16x8*)(Qbase + (size_t)(kk * 1536 + m0 + 32 + fm) * 32);
#pragma unroll
        for (int mt = 0; mt < 8; mt++) {
            bf16x8 ak = *(const bf16x8*)(Kbase + (size_t)(kk * 512 + w * 128 + mt * 16 + fm) * 32);
            acc[mt][0] = __builtin_amdgcn_mfma_f32_16x16x32_bf16(ak, bq0, acc[mt][0], 0, 0, 0);
            acc[mt][1] = __builtin_amdgcn_mfma_f32_16x16x32_bf16(ak, bq1, acc[mt][1], 0, 0, 0);
            acc[mt][2] = __builtin_amdgcn_mfma_f32_16x16x32_bf16(ak, bq2, acc[mt][2], 0, 0, 0);
        }
    }

    // V prefetch, first half: overlaps with exp/pack/barrier below (T14)
    bf16x8 vpre[8];
#pragma unroll
    for (int kk = 0; kk < 8; kk++)
        vpre[kk] = *(const bf16x8*)(Vbase + (size_t)kk * 64 * 32);

    // phase 2: e = exp(s), pack bf16 to LDS, column sums per q-group
    float s0 = 0.f, s1 = 0.f, s2 = 0.f;
#pragma unroll
    for (int mt = 0; mt < 8; mt++) {
        int kb = w * 128 + mt * 16 + quad * 4;
        float e00 = __expf(acc[mt][0][0]);
        float e01 = __expf(acc[mt][0][1]);
        float e02 = __expf(acc[mt][0][2]);
        float e03 = __expf(acc[mt][0][3]);
        s0 += (e00 + e01) + (e02 + e03);
        uint2 p0; p0.x = pkbf(e00, e01); p0.y = pkbf(e02, e03);
        *(uint2*)(P + (size_t)fm * 520 + kb) = p0;
        float e10 = __expf(acc[mt][1][0]);
        float e11 = __expf(acc[mt][1][1]);
        float e12 = __expf(acc[mt][1][2]);
        float e13 = __expf(acc[mt][1][3]);
        s1 += (e10 + e11) + (e12 + e13);
        uint2 p1; p1.x = pkbf(e10, e11); p1.y = pkbf(e12, e13);
        *(uint2*)(P + (size_t)(16 + fm) * 520 + kb) = p1;
        float e20 = __expf(acc[mt][2][0]);
        float e21 = __expf(acc[mt][2][1]);
        float e22 = __expf(acc[mt][2][2]);
        float e23 = __expf(acc[mt][2][3]);
        s2 += (e20 + e21) + (e22 + e23);
        uint2 p2; p2.x = pkbf(e20, e21); p2.y = pkbf(e22, e23);
        *(uint2*)(P + (size_t)(32 + fm) * 520 + kb) = p2;
    }
    s0 += __shfl_xor(s0, 16, 64); s0 += __shfl_xor(s0, 32, 64);
    s1 += __shfl_xor(s1, 16, 64); s1 += __shfl_xor(s1, 32, 64);
    s2 += __shfl_xor(s2, 16, 64); s2 += __shfl_xor(s2, 32, 64);
    if (quad == 0) {
        redsum[w * 48 + fm] = s0;
        redsum[w * 48 + 16 + fm] = s1;
        redsum[w * 48 + 32 + fm] = s2;
    }
    __syncthreads();

    // phase 3: O^T = V^T P; second-half V loads issued first, then MFMA loop
    float inv0 = 1.f / (redsum[fm] + redsum[48 + fm] + redsum[96 + fm] + redsum[144 + fm]);
    float inv1 = 1.f / (redsum[16 + fm] + redsum[64 + fm] + redsum[112 + fm] + redsum[160 + fm]);
    float inv2 = 1.f / (redsum[32 + fm] + redsum[80 + fm] + redsum[128 + fm] + redsum[176 + fm]);
    bf16x8 vrest[8];
#pragma unroll
    for (int kk = 0; kk < 8; kk++)
        vrest[kk] = *(const bf16x8*)(Vbase + (size_t)(8 + kk) * 64 * 32);
    f32x4 z = {0.f, 0.f, 0.f, 0.f};
    f32x4 o0 = z, o1 = z, o2 = z;
    const unsigned short* Pp0 = P + (size_t)fm * 520 + quad * 8;
    const unsigned short* Pp1 = P + (size_t)(16 + fm) * 520 + quad * 8;
    const unsigned short* Pp2 = P + (size_t)(32 + fm) * 520 + quad * 8;
#pragma unroll
    for (int kk = 0; kk < 8; kk++) {
        bf16x8 p0 = *(const bf16x8*)(Pp0 + kk * 32);
        bf16x8 p1 = *(const bf16x8*)(Pp1 + kk * 32);
        bf16x8 p2 = *(const bf16x8*)(Pp2 + kk * 32);
        o0 = __builtin_amdgcn_mfma_f32_16x16x32_bf16(vpre[kk], p0, o0, 0, 0, 0);
        o1 = __builtin_amdgcn_mfma_f32_16x16x32_bf16(vpre[kk], p1, o1, 0, 0, 0);
        o2 = __builtin_amdgcn_mfma_f32_16x16x32_bf16(vpre[kk], p2, o2, 0, 0, 0);
    }
#pragma unroll
    for (int kk = 0; kk < 8; kk++) {
        bf16x8 p0 = *(const bf16x8*)(Pp0 + (8 + kk) * 32);
        bf16x8 p1 = *(const bf16x8*)(Pp1 + (8 + kk) * 32);
        bf16x8 p2 = *(const bf16x8*)(Pp2 + (8 + kk) * 32);
        o0 = __builtin_amdgcn_mfma_f32_16x16x32_bf16(vrest[kk], p0, o0, 0, 0, 0);
        o1 = __builtin_amdgcn_mfma_f32_16x16x32_bf16(vrest[kk], p1, o1, 0, 0, 0);
        o2 = __builtin_amdgcn_mfma_f32_16x16x32_bf16(vrest[kk], p2, o2, 0, 0, 0);
    }
    ushort4 r0, r1, r2;
    r0.x = f2bf(o0[0] * inv0); r0.y = f2bf(o0[1] * inv0);
    r0.z = f2bf(o0[2] * inv0); r0.w = f2bf(o0[3] * inv0);
    r1.x = f2bf(o1[0] * inv1); r1.y = f2bf(o1[1] * inv1);
    r1.z = f2bf(o1[2] * inv1); r1.w = f2bf(o1[3] * inv1);
    r2.x = f2bf(o2[0] * inv2); r2.y = f2bf(o2[1] * inv2);
    r2.z = f2bf(o2[2] * inv2); r2.w = f2bf(o2[3] * inv2);
    size_t col = h * HD + w * 16 + quad * 4;
    *(ushort4*)(attn + ((size_t)(b * 1536 + m0 + fm)) * DD + col) = r0;
    *(ushort4*)(attn + ((size_t)(b * 1536 + m0 + 16 + fm)) * DD + col) = r1;
    *(ushort4*)(attn + ((size_t)(b * 1536 + m0 + 32 + fm)) * DD + col) = r2;
}

// ---------------------------------------------------------------------------
extern "C" void kernel_launch(void* const* d_in, const int* in_sizes, int n_in,
                              void* d_out, int out_size, void* d_ws, size_t ws_size,
                              hipStream_t stream)
{
    const float* x1   = (const float*)d_in[0];
    const float* x2   = (const float*)d_in[1];
    const float* x3   = (const float*)d_in[2];
    const float* xf   = (const float*)d_in[3];
    const float* emb  = (const float*)d_in[4];
    const unsigned char* mask = (const unsigned char*)d_in[5];
    const float* adaln_w = (const float*)d_in[6];
    const float* adaln_b = (const float*)d_in[7];
    const float* xf_w = (const float*)d_in[8];
    const float* xf_b = (const float*)d_in[9];
    const float* q_w  = (const float*)d_in[10];
    const float* q_b  = (const float*)d_in[11];
    const float* k_w  = (const float*)d_in[12];
    const float* k_b  = (const float*)d_in[13];
    const float* v_w  = (const float*)d_in[14];
    const float* v_b  = (const float*)d_in[15];
    const float* out_w = (const float*)d_in[16];
    const float* out_b = (const float*)d_in[17];

    char* ws = (char*)d_ws;
    float* scaleB        = (float*)(ws + 0);
    float* shiftB        = (float*)(ws + 65536);
    unsigned short* hq   = (unsigned short*)(ws + 131072);     // 12.58 MB (reused for attn out)
    unsigned short* hx   = (unsigned short*)(ws + 12713984);   // 4.19 MB
    unsigned short* Qpk  = (unsigned short*)(ws + 16908288);   // 12.58 MB
    unsigned short* Kpk  = (unsigned short*)(ws + 29491200);   // 4.19 MB
    unsigned short* Vpk  = (unsigned short*)(ws + 33685504);   // 4.19 MB
    unsigned short* qwt  = (unsigned short*)(ws + 37879808);   // 6.29 MB
    unsigned short* kwt  = (unsigned short*)(ws + 44171264);   // 2.10 MB
    unsigned short* vwt  = (unsigned short*)(ws + 46268416);   // 2.10 MB
    unsigned short* owt  = (unsigned short*)(ws + 48365568);   // 6.29 MB (end ~54.7 MB)

    tw_all_kernel<<<dim3(16, 16, 8), 256, 0, stream>>>(q_w, k_w, v_w, out_w,
                                                       qwt, kwt, vwt, owt);
    adaln_kernel<<<dim3(64, 4), 256, 0, stream>>>(emb, adaln_w, adaln_b, xf_w, xf_b,
                                                  scaleB, shiftB);
    ln_mod_kernel<<<8192, 256, 0, stream>>>(x1, x2, x3, xf, scaleB, shiftB, hq, hx);
    qkv_gemm<<<1280, 256, 0, stream>>>(hq, hx, qwt, kwt, vwt, q_b, k_b, v_b,
                                       Qpk, Kpk, Vpk);
    attn_kernel<<<2048, 256, 0, stream>>>(Qpk, Kpk, Vpk, mask, hq);
    out_gemm<<<768, 256, 0, stream>>>(hq, owt, out_b, (float*)d_out);
}

// Round 11
// 256.959 us; speedup vs baseline: 1.0062x; 1.0062x over previous
//
#include <hip/hip_runtime.h>
#include <hip/hip_bf16.h>
#include <stdint.h>

#define BB 4
#define TSEQ 512
#define NSEQ 512
#define DD 1024
#define EE 1024
#define HH 16
#define HD 64

typedef __attribute__((ext_vector_type(8))) short bf16x8;
typedef __attribute__((ext_vector_type(4))) float f32x4;

__device__ __forceinline__ unsigned short f2bf(float f) {
    union { float f; uint32_t u; } v; v.f = f;
    uint32_t u = v.u;
    uint32_t r = (u + 0x7fffu + ((u >> 16) & 1u)) >> 16;
    return (unsigned short)r;
}

__device__ __forceinline__ uint32_t pkbf(float a, float b) {
    __hip_bfloat162 t = __float22bfloat162_rn(float2{a, b});
    return *(uint32_t*)&t;
}

#define GLD16(gp, lp)                                                          \
    __builtin_amdgcn_global_load_lds(                                          \
        (const __attribute__((address_space(1))) unsigned int*)(gp),           \
        (__attribute__((address_space(3))) unsigned int*)(lp), 16, 0, 0)

// ---------------------------------------------------------------------------
// K1: merged weight transpose+cvt (blocks 0..2047) and adaln (blocks
// 2048..2303). The two halves are data-independent; merging removes one
// launch boundary and lets them co-schedule. LDS: shared raw buffer sized
// for the larger (adaln) half: 16384 (seT) + 16896 (buf) = 33280 B.
// ---------------------------------------------------------------------------
__global__ __launch_bounds__(256) void prep_kernel(
    const float* __restrict__ q_w, const float* __restrict__ k_w,
    const float* __restrict__ v_w, const float* __restrict__ out_w,
    unsigned short* __restrict__ qwt, unsigned short* __restrict__ kwt,
    unsigned short* __restrict__ vwt, unsigned short* __restrict__ owt,
    const float* __restrict__ emb,
    const float* __restrict__ adaln_w, const float* __restrict__ adaln_b,
    const float* __restrict__ xf_w, const float* __restrict__ xf_b,
    float* __restrict__ scaleB, float* __restrict__ shiftB)
{
    __shared__ __align__(16) char lds_raw[33280];
    int id = blockIdx.x, tid = threadIdx.x;
    if (id < 2048) {
        // ---- weight transpose+cvt half (was tw_all_kernel, dim3(16,16,8)) ----
        unsigned short* Ts = (unsigned short*)lds_raw;   // 64*72 shorts
        int k0 = (id & 15) * 64, n0 = ((id >> 4) & 15) * 64;
        int z = id >> 8;
        const float* in; unsigned short* out;
        if (z < 3)       { in = q_w + (size_t)z * DD * DD;         out = qwt + (size_t)z * DD * DD; }
        else if (z == 3) { in = k_w;                               out = kwt; }
        else if (z == 4) { in = v_w;                               out = vwt; }
        else             { in = out_w + (size_t)(z - 5) * DD * DD; out = owt + (size_t)(z - 5) * DD * DD; }
        int r = tid >> 2, c0 = (tid & 3) * 16;
#pragma unroll
        for (int i = 0; i < 4; i++) {
            float4 v = *(const float4*)(in + (size_t)(k0 + r) * DD + n0 + c0 + i * 4);
            Ts[(c0 + i * 4 + 0) * 72 + r] = f2bf(v.x);
            Ts[(c0 + i * 4 + 1) * 72 + r] = f2bf(v.y);
            Ts[(c0 + i * 4 + 2) * 72 + r] = f2bf(v.z);
            Ts[(c0 + i * 4 + 3) * 72 + r] = f2bf(v.w);
        }
        __syncthreads();
#pragma unroll
        for (int i = 0; i < 2; i++) {
            int idx = i * 256 + tid;
            int row = idx >> 3, ko = (idx & 7) * 8;
            *(uint4*)(out + (size_t)(n0 + row) * DD + k0 + ko) =
                *(const uint4*)(Ts + row * 72 + ko);
        }
    } else {
        // ---- adaln half (was adaln_kernel, dim3(64,4)) ----
        float* seT = (float*)lds_raw;                    // [EE][4]
        float* buf = (float*)(lds_raw + 16384);          // [128*33]
        int a = id - 2048;
        int chunk = a & 63, j = a >> 6;
#pragma unroll
        for (int b = 0; b < 4; b++) {
            float4 e4 = ((const float4*)(emb + (size_t)b * EE))[tid];
            seT[(tid * 4 + 0) * 4 + b] = e4.x / (1.f + __expf(-e4.x));
            seT[(tid * 4 + 1) * 4 + b] = e4.y / (1.f + __expf(-e4.y));
            seT[(tid * 4 + 2) * 4 + b] = e4.z / (1.f + __expf(-e4.z));
            seT[(tid * 4 + 3) * 4 + b] = e4.w / (1.f + __expf(-e4.w));
        }
        __syncthreads();
        const float* W    = (j < 3) ? (adaln_w + (size_t)j * EE * 2 * DD) : xf_w;
        const float* bias = (j < 3) ? (adaln_b + (size_t)j * 2 * DD) : xf_b;
        int eg = tid >> 3, cg = tid & 7;
        int c0 = chunk * 32 + cg * 4;
        const float* Wp = W + (size_t)(eg * 32) * (2 * DD) + c0;
        float4 a0 = {0,0,0,0}, a1 = {0,0,0,0}, a2 = {0,0,0,0}, a3 = {0,0,0,0};
#pragma unroll 8
        for (int e = 0; e < 32; e++) {
            float4 w = *(const float4*)(Wp + (size_t)e * (2 * DD));
            float4 s = *(const float4*)(seT + (eg * 32 + e) * 4);
            a0.x += s.x * w.x; a0.y += s.x * w.y; a0.z += s.x * w.z; a0.w += s.x * w.w;
            a1.x += s.y * w.x; a1.y += s.y * w.y; a1.z += s.y * w.z; a1.w += s.y * w.w;
            a2.x += s.z * w.x; a2.y += s.z * w.y; a2.z += s.z * w.z; a2.w += s.z * w.w;
            a3.x += s.w * w.x; a3.y += s.w * w.y; a3.z += s.w * w.z; a3.w += s.w * w.w;
        }
        float accs[4][4] = {{a0.x,a0.y,a0.z,a0.w},{a1.x,a1.y,a1.z,a1.w},
                            {a2.x,a2.y,a2.z,a2.w},{a3.x,a3.y,a3.z,a3.w}};
#pragma unroll
        for (int b = 0; b < 4; b++)
#pragma unroll
            for (int i = 0; i < 4; i++)
                buf[(b * 32 + cg * 4 + i) * 33 + eg] = accs[b][i];
        __syncthreads();
        if (tid < 128) {
            int b = tid >> 5, cl = tid & 31;
            float s = 0.f;
#pragma unroll 8
            for (int e = 0; e < 32; e++) s += buf[(b * 32 + cl) * 33 + e];
            int c = chunk * 32 + cl;
            float v = s + bias[c];
            if (c < DD) scaleB[(size_t)(j * 4 + b) * DD + c] = v;
            else        shiftB[(size_t)(j * 4 + b) * DD + (c - DD)] = v;
        }
    }
}

// ---------------------------------------------------------------------------
// K2: LayerNorm + modulate, cast bf16
// ---------------------------------------------------------------------------
__global__ __launch_bounds__(256) void ln_mod_kernel(
    const float* __restrict__ x1, const float* __restrict__ x2,
    const float* __restrict__ x3, const float* __restrict__ xf,
    const float* __restrict__ scaleB, const float* __restrict__ shiftB,
    unsigned short* __restrict__ hq, unsigned short* __restrict__ hx)
{
    __shared__ float rs[4], rq[4];
    int row = blockIdx.x, tid = threadIdx.x;
    const float* src; unsigned short* dst; int sb;
    if (row < 6144) {
        int b = row / 1536, t3 = row % 1536;
        int br = t3 >> 9, t = t3 & 511;
        const float* xs = (br == 0) ? x1 : ((br == 1) ? x2 : x3);
        src = xs + ((size_t)b * TSEQ + t) * DD;
        dst = hq + (size_t)row * DD;
        sb = br * 4 + b;
    } else {
        int idx = row - 6144;
        src = xf + (size_t)idx * DD;
        dst = hx + (size_t)idx * DD;
        sb = 12 + (idx >> 9);
    }
    float4 x = ((const float4*)src)[tid];
    float s = x.x + x.y + x.z + x.w;
    float q = x.x * x.x + x.y * x.y + x.z * x.z + x.w * x.w;
    for (int o = 1; o < 64; o <<= 1) { s += __shfl_xor(s, o, 64); q += __shfl_xor(q, o, 64); }
    int lane = tid & 63, wid = tid >> 6;
    if (lane == 0) { rs[wid] = s; rq[wid] = q; }
    __syncthreads();
    float S = rs[0] + rs[1] + rs[2] + rs[3];
    float Q = rq[0] + rq[1] + rq[2] + rq[3];
    float mu = S * (1.f / DD);
    float var = Q * (1.f / DD) - mu * mu;
    float rstd = rsqrtf(var + 1e-6f);
    float4 sc = ((const float4*)(scaleB + (size_t)sb * DD))[tid];
    float4 sh = ((const float4*)(shiftB + (size_t)sb * DD))[tid];
    ushort4 o;
    o.x = f2bf((x.x - mu) * rstd * (1.f + sc.x) + sh.x);
    o.y = f2bf((x.y - mu) * rstd * (1.f + sc.y) + sh.y);
    o.z = f2bf((x.z - mu) * rstd * (1.f + sc.z) + sh.z);
    o.w = f2bf((x.w - mu) * rstd * (1.f + sc.w) + sh.w);
    ((ushort4*)dst)[tid] = o;
}

// ---------------------------------------------------------------------------
// GEMM core: 128x64 tile, BK=64, conflict-free XOR swizzle, 4 waves 2x2.
// (R2-verified best config; all later restructures were neutral or worse.)
// ---------------------------------------------------------------------------
__device__ __forceinline__ void gemm_core64(
    const unsigned short* __restrict__ A, const unsigned short* __restrict__ W,
    int m0, int n0, unsigned short* As, unsigned short* Bs,
    int tid, f32x4 acc[4][2])
{
    int lane = tid & 63, wid = tid >> 6;
    int fm = lane & 15, quad = lane >> 4;
    int wm = wid >> 1, wn = wid & 1;
    int sr = tid >> 3;                    // row 0..31
    int sc = tid & 7;                     // LDS chunk position 0..7
    int gko = (sc ^ (sr & 7)) * 8;        // global k-chunk landing at pos sc
    const unsigned short* Ap = A + (size_t)(m0 + sr) * DD + gko;
    const unsigned short* Wp = W + (size_t)(n0 + sr) * DD + gko;
    unsigned short* la = As + tid * 8;    // = sr*64 + sc*8
    unsigned short* lb = Bs + tid * 8;
    int f7 = fm & 7;
    for (int k0 = 0; k0 < DD; k0 += 64) {
#pragma unroll
        for (int i = 0; i < 4; i++)
            GLD16(Ap + (size_t)(32 * i) * DD + k0, la + i * 2048);
#pragma unroll
        for (int i = 0; i < 2; i++)
            GLD16(Wp + (size_t)(32 * i) * DD + k0, lb + i * 2048);
        __syncthreads();
#pragma unroll
        for (int kh = 0; kh < 2; kh++) {
            int sq = ((quad + 4 * kh) ^ f7) * 8;
            bf16x8 af[4], bfr[2];
#pragma unroll
            for (int mt = 0; mt < 4; mt++)
                af[mt] = *(const bf16x8*)(As + (wm * 64 + mt * 16 + fm) * 64 + sq);
#pragma unroll
            for (int nt = 0; nt < 2; nt++)
                bfr[nt] = *(const bf16x8*)(Bs + (wn * 32 + nt * 16 + fm) * 64 + sq);
#pragma unroll
            for (int mt = 0; mt < 4; mt++)
#pragma unroll
                for (int nt = 0; nt < 2; nt++)
                    acc[mt][nt] = __builtin_amdgcn_mfma_f32_16x16x32_bf16(af[mt], bfr[nt], acc[mt][nt], 0, 0, 0);
        }
        __syncthreads();
    }
}

// ---------------------------------------------------------------------------
// K3: fused Q/K/V projection -> MFMA-fragment-packed outputs.
// flat grid 1280: m-tile = id % 80 (XCD-affine), n-tile(64) = id / 80.
// (R2 mapping restored; R10's head-affine factorization cost +27MB FETCH.)
// ---------------------------------------------------------------------------
__global__ __launch_bounds__(256) void qkv_gemm(
    const unsigned short* __restrict__ hq, const unsigned short* __restrict__ hx,
    const unsigned short* __restrict__ qwt, const unsigned short* __restrict__ kwt,
    const unsigned short* __restrict__ vwt,
    const float* __restrict__ q_b, const float* __restrict__ k_b,
    const float* __restrict__ v_b,
    unsigned short* __restrict__ Qpk, unsigned short* __restrict__ Kpk,
    unsigned short* __restrict__ Vpk)
{
    __shared__ __align__(16) unsigned short As[128 * 64];
    __shared__ __align__(16) unsigned short Bs[64 * 64];
    int id = blockIdx.x;
    int ty = id % 80, n0 = (id / 80) * 64;
    const unsigned short *A, *W; const float* bias; int mode, m0;
    if (ty < 48) {
        m0 = ty * 128;
        int br = (m0 % 1536) >> 9;
        A = hq; W = qwt + (size_t)br * DD * DD; bias = q_b + (size_t)br * DD; mode = 0;
    } else if (ty < 64) {
        m0 = (ty - 48) * 128; A = hx; W = kwt; bias = k_b; mode = 1;
    } else {
        m0 = (ty - 64) * 128; A = hx; W = vwt; bias = v_b; mode = 2;
    }
    int tid = threadIdx.x, lane = tid & 63, wid = tid >> 6;
    int fm = lane & 15, quad = lane >> 4;
    int wm = wid >> 1, wn = wid & 1;
    f32x4 z = {0.f, 0.f, 0.f, 0.f};
    f32x4 acc[4][2];
#pragma unroll
    for (int mt = 0; mt < 4; mt++)
#pragma unroll
        for (int nt = 0; nt < 2; nt++) acc[mt][nt] = z;
    gemm_core64(A, W, m0, n0, As, Bs, tid, acc);
#pragma unroll
    for (int mt = 0; mt < 4; mt++) {
#pragma unroll
        for (int nt = 0; nt < 2; nt++) {
            int c = n0 + wn * 32 + nt * 16 + fm;
            float bv = bias[c];
            int r0 = m0 + wm * 64 + mt * 16 + quad * 4;
            int h = c >> 6;
            if (mode == 0) {
                int b = r0 / 1536, t3 = r0 % 1536;
                int kk = (c >> 5) & 1, o = c & 31;
                size_t base = ((((size_t)(b * HH + h) * 2 + kk) * 1536) + t3) * 32 + o;
#pragma unroll
                for (int reg = 0; reg < 4; reg++)
                    Qpk[base + (size_t)reg * 32] = f2bf((acc[mt][nt][reg] + bv) * 0.125f);
            } else if (mode == 1) {
                int b = r0 >> 9, n = r0 & 511;
                int kk = (c >> 5) & 1, o = c & 31;
                size_t base = ((((size_t)(b * HH + h) * 2 + kk) * 512) + n) * 32 + o;
#pragma unroll
                for (int reg = 0; reg < 4; reg++)
                    Kpk[base + (size_t)reg * 32] = f2bf(acc[mt][nt][reg] + bv);
            } else {
                int b = r0 >> 9, n = r0 & 511;
                int hd = c & 63, cv = n >> 5, ko = n & 31;
                ushort4 st;
                st.x = f2bf(acc[mt][nt][0] + bv);
                st.y = f2bf(acc[mt][nt][1] + bv);
                st.z = f2bf(acc[mt][nt][2] + bv);
                st.w = f2bf(acc[mt][nt][3] + bv);
                *(ushort4*)(Vpk + ((((size_t)(b * HH + h) * 16 + cv) * 64) + hd) * 32 + ko) = st;
            }
        }
    }
}

// ---------------------------------------------------------------------------
// K5: out projection, fp32 out remapped branch-major. flat grid 768:
// m = id % 48 (XCD-affine), n-tile(64) = id / 48.
// ---------------------------------------------------------------------------
__global__ __launch_bounds__(256) void out_gemm(
    const unsigned short* __restrict__ Ain, const unsigned short* __restrict__ owt,
    const float* __restrict__ out_b, float* __restrict__ outp)
{
    __shared__ __align__(16) unsigned short As[128 * 64];
    __shared__ __align__(16) unsigned short Bs[64 * 64];
    int id = blockIdx.x;
    int m0 = (id % 48) * 128, n0 = (id / 48) * 64;
    int br = (m0 % 1536) >> 9;
    const unsigned short* W = owt + (size_t)br * DD * DD;
    const float* bias = out_b + (size_t)br * DD;
    int tid = threadIdx.x, lane = tid & 63, wid = tid >> 6;
    int fm = lane & 15, quad = lane >> 4;
    int wm = wid >> 1, wn = wid & 1;
    f32x4 z = {0.f, 0.f, 0.f, 0.f};
    f32x4 acc[4][2];
#pragma unroll
    for (int mt = 0; mt < 4; mt++)
#pragma unroll
        for (int nt = 0; nt < 2; nt++) acc[mt][nt] = z;
    gemm_core64(Ain, W, m0, n0, As, Bs, tid, acc);
#pragma unroll
    for (int mt = 0; mt < 4; mt++) {
#pragma unroll
        for (int nt = 0; nt < 2; nt++) {
            int c = n0 + wn * 32 + nt * 16 + fm;
            float bv = bias[c];
            int r0 = m0 + wm * 64 + mt * 16 + quad * 4;
            int b = r0 / 1536, t3 = r0 % 1536, t = t3 & 511;
#pragma unroll
            for (int reg = 0; reg < 4; reg++)
                outp[(size_t)br * (BB * TSEQ * DD) + (size_t)b * (TSEQ * DD)
                     + (size_t)(t + reg) * DD + c] = acc[mt][nt][reg] + bv;
        }
    }
}

// ---------------------------------------------------------------------------
// K4: attention, 48 queries/block (R9-verified best: 255.8us). Blocks/head 32;
// per-XCD 8 consecutive heads x 32 m-tiles = 256 blocks, bijective swizzle.
// LDS 50.7KB -> 3 blocks/CU, 12 waves. T14 V-prefetch retained.
// ---------------------------------------------------------------------------
__global__ __launch_bounds__(256, 3) void attn_kernel(
    const unsigned short* __restrict__ Qpk,
    const unsigned short* __restrict__ Kpk,
    const unsigned short* __restrict__ Vpk,
    const unsigned char* __restrict__ mask,
    unsigned short* __restrict__ attn)
{
    __shared__ __align__(16) unsigned short P[48 * 520];
    __shared__ float redsum[4 * 48];
    // bijective XCD swizzle: 2048 blocks, 8 XCDs, 256 per XCD
    int orig = blockIdx.x;
    int wg = (orig & 7) * 256 + (orig >> 3);
    int bh = wg / 32, b = bh >> 4, h = bh & 15;
    int m0 = (wg % 32) * 48;
    int tid = threadIdx.x, lane = tid & 63, w = tid >> 6;
    int fm = lane & 15, quad = lane >> 4;

    const unsigned char* mp = mask + (size_t)b * NSEQ + w * 128;
    unsigned long long mw0 = __ballot(mp[lane] != 0);
    unsigned long long mw1 = __ballot(mp[64 + lane] != 0);

    // phase 1: S^T = K (Q/8)^T for 48 queries, mask as C-init
    f32x4 acc[8][3];
#pragma unroll
    for (int mt = 0; mt < 8; mt++) {
        unsigned long long word = (mt >= 4) ? mw1 : mw0;
        int kb = (mt * 16 + quad * 4) & 63;
        f32x4 ini;
#pragma unroll
        for (int reg = 0; reg < 4; reg++)
            ini[reg] = ((word >> (kb + reg)) & 1ull) ? -1e30f : 0.f;
        acc[mt][0] = ini; acc[mt][1] = ini; acc[mt][2] = ini;
    }
    const unsigned short* Kbase = Kpk + (size_t)bh * 2 * 512 * 32 + quad * 8;
    const unsigned short* Qbase = Qpk + (size_t)bh * 2 * 1536 * 32 + quad * 8;
    const unsigned short* Vbase = Vpk + (size_t)bh * 16 * 64 * 32 + (size_t)(w * 16 + fm) * 32 + quad * 8;
#pragma unroll
    for (int kk = 0; kk < 2; kk++) {
        bf16x8 bq0 = *(const bf16x8*)(Qbase + (size_t)(kk * 1536 + m0 + fm) * 32);
        bf16x8 bq1 = *(const bf16x8*)(Qbase + (size_t)(kk * 1536 + m0 + 16 + fm) * 32);
        bf16x8 bq2 = *(const bf16x8*)(Qbase + (size_t)(kk * 1536 + m0 + 32 + fm) * 32);
#pragma unroll
        for (int mt = 0; mt < 8; mt++) {
            bf16x8 ak = *(const bf16x8*)(Kbase + (size_t)(kk * 512 + w * 128 + mt * 16 + fm) * 32);
            acc[mt][0] = __builtin_amdgcn_mfma_f32_16x16x32_bf16(ak, bq0, acc[mt][0], 0, 0, 0);
            acc[mt][1] = __builtin_amdgcn_mfma_f32_16x16x32_bf16(ak, bq1, acc[mt][1], 0, 0, 0);
            acc[mt][2] = __builtin_amdgcn_mfma_f32_16x16x32_bf16(ak, bq2, acc[mt][2], 0, 0, 0);
        }
    }

    // V prefetch, first half: overlaps with exp/pack/barrier below (T14)
    bf16x8 vpre[8];
#pragma unroll
    for (int kk = 0; kk < 8; kk++)
        vpre[kk] = *(const bf16x8*)(Vbase + (size_t)kk * 64 * 32);

    // phase 2: e = exp(s), pack bf16 to LDS, column sums per q-group
    float s0 = 0.f, s1 = 0.f, s2 = 0.f;
#pragma unroll
    for (int mt = 0; mt < 8; mt++) {
        int kb = w * 128 + mt * 16 + quad * 4;
        float e00 = __expf(acc[mt][0][0]);
        float e01 = __expf(acc[mt][0][1]);
        float e02 = __expf(acc[mt][0][2]);
        float e03 = __expf(acc[mt][0][3]);
        s0 += (e00 + e01) + (e02 + e03);
        uint2 p0; p0.x = pkbf(e00, e01); p0.y = pkbf(e02, e03);
        *(uint2*)(P + (size_t)fm * 520 + kb) = p0;
        float e10 = __expf(acc[mt][1][0]);
        float e11 = __expf(acc[mt][1][1]);
        float e12 = __expf(acc[mt][1][2]);
        float e13 = __expf(acc[mt][1][3]);
        s1 += (e10 + e11) + (e12 + e13);
        uint2 p1; p1.x = pkbf(e10, e11); p1.y = pkbf(e12, e13);
        *(uint2*)(P + (size_t)(16 + fm) * 520 + kb) = p1;
        float e20 = __expf(acc[mt][2][0]);
        float e21 = __expf(acc[mt][2][1]);
        float e22 = __expf(acc[mt][2][2]);
        float e23 = __expf(acc[mt][2][3]);
        s2 += (e20 + e21) + (e22 + e23);
        uint2 p2; p2.x = pkbf(e20, e21); p2.y = pkbf(e22, e23);
        *(uint2*)(P + (size_t)(32 + fm) * 520 + kb) = p2;
    }
    s0 += __shfl_xor(s0, 16, 64); s0 += __shfl_xor(s0, 32, 64);
    s1 += __shfl_xor(s1, 16, 64); s1 += __shfl_xor(s1, 32, 64);
    s2 += __shfl_xor(s2, 16, 64); s2 += __shfl_xor(s2, 32, 64);
    if (quad == 0) {
        redsum[w * 48 + fm] = s0;
        redsum[w * 48 + 16 + fm] = s1;
        redsum[w * 48 + 32 + fm] = s2;
    }
    __syncthreads();

    // phase 3: O^T = V^T P; second-half V loads issued first, then MFMA loop
    float inv0 = 1.f / (redsum[fm] + redsum[48 + fm] + redsum[96 + fm] + redsum[144 + fm]);
    float inv1 = 1.f / (redsum[16 + fm] + redsum[64 + fm] + redsum[112 + fm] + redsum[160 + fm]);
    float inv2 = 1.f / (redsum[32 + fm] + redsum[80 + fm] + redsum[128 + fm] + redsum[176 + fm]);
    bf16x8 vrest[8];
#pragma unroll
    for (int kk = 0; kk < 8; kk++)
        vrest[kk] = *(const bf16x8*)(Vbase + (size_t)(8 + kk) * 64 * 32);
    f32x4 z = {0.f, 0.f, 0.f, 0.f};
    f32x4 o0 = z, o1 = z, o2 = z;
    const unsigned short* Pp0 = P + (size_t)fm * 520 + quad * 8;
    const unsigned short* Pp1 = P + (size_t)(16 + fm) * 520 + quad * 8;
    const unsigned short* Pp2 = P + (size_t)(32 + fm) * 520 + quad * 8;
#pragma unroll
    for (int kk = 0; kk < 8; kk++) {
        bf16x8 p0 = *(const bf16x8*)(Pp0 + kk * 32);
        bf16x8 p1 = *(const bf16x8*)(Pp1 + kk * 32);
        bf16x8 p2 = *(const bf16x8*)(Pp2 + kk * 32);
        o0 = __builtin_amdgcn_mfma_f32_16x16x32_bf16(vpre[kk], p0, o0, 0, 0, 0);
        o1 = __builtin_amdgcn_mfma_f32_16x16x32_bf16(vpre[kk], p1, o1, 0, 0, 0);
        o2 = __builtin_amdgcn_mfma_f32_16x16x32_bf16(vpre[kk], p2, o2, 0, 0, 0);
    }
#pragma unroll
    for (int kk = 0; kk < 8; kk++) {
        bf16x8 p0 = *(const bf16x8*)(Pp0 + (8 + kk) * 32);
        bf16x8 p1 = *(const bf16x8*)(Pp1 + (8 + kk) * 32);
        bf16x8 p2 = *(const bf16x8*)(Pp2 + (8 + kk) * 32);
        o0 = __builtin_amdgcn_mfma_f32_16x16x32_bf16(vrest[kk], p0, o0, 0, 0, 0);
        o1 = __builtin_amdgcn_mfma_f32_16x16x32_bf16(vrest[kk], p1, o1, 0, 0, 0);
        o2 = __builtin_amdgcn_mfma_f32_16x16x32_bf16(vrest[kk], p2, o2, 0, 0, 0);
    }
    ushort4 r0, r1, r2;
    r0.x = f2bf(o0[0] * inv0); r0.y = f2bf(o0[1] * inv0);
    r0.z = f2bf(o0[2] * inv0); r0.w = f2bf(o0[3] * inv0);
    r1.x = f2bf(o1[0] * inv1); r1.y = f2bf(o1[1] * inv1);
    r1.z = f2bf(o1[2] * inv1); r1.w = f2bf(o1[3] * inv1);
    r2.x = f2bf(o2[0] * inv2); r2.y = f2bf(o2[1] * inv2);
    r2.z = f2bf(o2[2] * inv2); r2.w = f2bf(o2[3] * inv2);
    size_t col = h * HD + w * 16 + quad * 4;
    *(ushort4*)(attn + ((size_t)(b * 1536 + m0 + fm)) * DD + col) = r0;
    *(ushort4*)(attn + ((size_t)(b * 1536 + m0 + 16 + fm)) * DD + col) = r1;
    *(ushort4*)(attn + ((size_t)(b * 1536 + m0 + 32 + fm)) * DD + col) = r2;
}

// ---------------------------------------------------------------------------
extern "C" void kernel_launch(void* const* d_in, const int* in_sizes, int n_in,
                              void* d_out, int out_size, void* d_ws, size_t ws_size,
                              hipStream_t stream)
{
    const float* x1   = (const float*)d_in[0];
    const float* x2   = (const float*)d_in[1];
    const float* x3   = (const float*)d_in[2];
    const float* xf   = (const float*)d_in[3];
    const float* emb  = (const float*)d_in[4];
    const unsigned char* mask = (const unsigned char*)d_in[5];
    const float* adaln_w = (const float*)d_in[6];
    const float* adaln_b = (const float*)d_in[7];
    const float* xf_w = (const float*)d_in[8];
    const float* xf_b = (const float*)d_in[9];
    const float* q_w  = (const float*)d_in[10];
    const float* q_b  = (const float*)d_in[11];
    const float* k_w  = (const float*)d_in[12];
    const float* k_b  = (const float*)d_in[13];
    const float* v_w  = (const float*)d_in[14];
    const float* v_b  = (const float*)d_in[15];
    const float* out_w = (const float*)d_in[16];
    const float* out_b = (const float*)d_in[17];

    char* ws = (char*)d_ws;
    float* scaleB        = (float*)(ws + 0);
    float* shiftB        = (float*)(ws + 65536);
    unsigned short* hq   = (unsigned short*)(ws + 131072);     // 12.58 MB (reused for attn out)
    unsigned short* hx   = (unsigned short*)(ws + 12713984);   // 4.19 MB
    unsigned short* Qpk  = (unsigned short*)(ws + 16908288);   // 12.58 MB
    unsigned short* Kpk  = (unsigned short*)(ws + 29491200);   // 4.19 MB
    unsigned short* Vpk  = (unsigned short*)(ws + 33685504);   // 4.19 MB
    unsigned short* qwt  = (unsigned short*)(ws + 37879808);   // 6.29 MB
    unsigned short* kwt  = (unsigned short*)(ws + 44171264);   // 2.10 MB
    unsigned short* vwt  = (unsigned short*)(ws + 46268416);   // 2.10 MB
    unsigned short* owt  = (unsigned short*)(ws + 48365568);   // 6.29 MB (end ~54.7 MB)

    prep_kernel<<<2304, 256, 0, stream>>>(q_w, k_w, v_w, out_w,
                                          qwt, kwt, vwt, owt,
                                          emb, adaln_w, adaln_b, xf_w, xf_b,
                                          scaleB, shiftB);
    ln_mod_kernel<<<8192, 256, 0, stream>>>(x1, x2, x3, xf, scaleB, shiftB, hq, hx);
    qkv_gemm<<<1280, 256, 0, stream>>>(hq, hx, qwt, kwt, vwt, q_b, k_b, v_b,
                                       Qpk, Kpk, Vpk);
    attn_kernel<<<2048, 256, 0, stream>>>(Qpk, Kpk, Vpk, mask, hq);
    out_gemm<<<768, 256, 0, stream>>>(hq, owt, out_b, (float*)d_out);
}

// Round 12
// 243.707 us; speedup vs baseline: 1.0609x; 1.0544x over previous
//
#include <hip/hip_runtime.h>
#include <hip/hip_bf16.h>
#include <stdint.h>

#define BB 4
#define TSEQ 512
#define NSEQ 512
#define DD 1024
#define EE 1024
#define HH 16
#define HD 64

typedef __attribute__((ext_vector_type(8))) short bf16x8;
typedef __attribute__((ext_vector_type(4))) float f32x4;

__device__ __forceinline__ unsigned short f2bf(float f) {
    union { float f; uint32_t u; } v; v.f = f;
    uint32_t u = v.u;
    uint32_t r = (u + 0x7fffu + ((u >> 16) & 1u)) >> 16;
    return (unsigned short)r;
}

__device__ __forceinline__ uint32_t pkbf(float a, float b) {
    __hip_bfloat162 t = __float22bfloat162_rn(float2{a, b});
    return *(uint32_t*)&t;
}

#define GLD16(gp, lp)                                                          \
    __builtin_amdgcn_global_load_lds(                                          \
        (const __attribute__((address_space(1))) unsigned int*)(gp),           \
        (__attribute__((address_space(3))) unsigned int*)(lp), 16, 0, 0)

// ---------------------------------------------------------------------------
// K1a: fused weight transpose+cvt for all 4 weight tensors
// ---------------------------------------------------------------------------
__global__ __launch_bounds__(256) void tw_all_kernel(
    const float* __restrict__ q_w, const float* __restrict__ k_w,
    const float* __restrict__ v_w, const float* __restrict__ out_w,
    unsigned short* __restrict__ qwt, unsigned short* __restrict__ kwt,
    unsigned short* __restrict__ vwt, unsigned short* __restrict__ owt)
{
    __shared__ __align__(16) unsigned short Ts[64 * 72];
    int k0 = blockIdx.x * 64, n0 = blockIdx.y * 64;
    int z = blockIdx.z;
    const float* in; unsigned short* out;
    if (z < 3)       { in = q_w + (size_t)z * DD * DD;         out = qwt + (size_t)z * DD * DD; }
    else if (z == 3) { in = k_w;                               out = kwt; }
    else if (z == 4) { in = v_w;                               out = vwt; }
    else             { in = out_w + (size_t)(z - 5) * DD * DD; out = owt + (size_t)(z - 5) * DD * DD; }
    int tid = threadIdx.x;
    int r = tid >> 2, c0 = (tid & 3) * 16;
#pragma unroll
    for (int i = 0; i < 4; i++) {
        float4 v = *(const float4*)(in + (size_t)(k0 + r) * DD + n0 + c0 + i * 4);
        Ts[(c0 + i * 4 + 0) * 72 + r] = f2bf(v.x);
        Ts[(c0 + i * 4 + 1) * 72 + r] = f2bf(v.y);
        Ts[(c0 + i * 4 + 2) * 72 + r] = f2bf(v.z);
        Ts[(c0 + i * 4 + 3) * 72 + r] = f2bf(v.w);
    }
    __syncthreads();
#pragma unroll
    for (int i = 0; i < 2; i++) {
        int idx = i * 256 + tid;
        int row = idx >> 3, ko = (idx & 7) * 8;
        *(uint4*)(out + (size_t)(n0 + row) * DD + k0 + ko) =
            *(const uint4*)(Ts + row * 72 + ko);
    }
}

// ---------------------------------------------------------------------------
// K1b: adaln. grid (64 col-chunks of 32, 4 branches), block 256.
// ---------------------------------------------------------------------------
__global__ __launch_bounds__(256) void adaln_kernel(
    const float* __restrict__ emb,
    const float* __restrict__ adaln_w, const float* __restrict__ adaln_b,
    const float* __restrict__ xf_w, const float* __restrict__ xf_b,
    float* __restrict__ scaleB, float* __restrict__ shiftB)
{
    __shared__ __align__(16) float seT[EE][4];
    __shared__ float buf[128 * 33];
    int tid = threadIdx.x;
    int chunk = blockIdx.x, j = blockIdx.y;
#pragma unroll
    for (int b = 0; b < 4; b++) {
        float4 e4 = ((const float4*)(emb + (size_t)b * EE))[tid];
        seT[tid * 4 + 0][b] = e4.x / (1.f + __expf(-e4.x));
        seT[tid * 4 + 1][b] = e4.y / (1.f + __expf(-e4.y));
        seT[tid * 4 + 2][b] = e4.z / (1.f + __expf(-e4.z));
        seT[tid * 4 + 3][b] = e4.w / (1.f + __expf(-e4.w));
    }
    __syncthreads();
    const float* W    = (j < 3) ? (adaln_w + (size_t)j * EE * 2 * DD) : xf_w;
    const float* bias = (j < 3) ? (adaln_b + (size_t)j * 2 * DD) : xf_b;
    int eg = tid >> 3, cg = tid & 7;
    int c0 = chunk * 32 + cg * 4;
    const float* Wp = W + (size_t)(eg * 32) * (2 * DD) + c0;
    float4 a0 = {0,0,0,0}, a1 = {0,0,0,0}, a2 = {0,0,0,0}, a3 = {0,0,0,0};
#pragma unroll 8
    for (int e = 0; e < 32; e++) {
        float4 w = *(const float4*)(Wp + (size_t)e * (2 * DD));
        float4 s = *(const float4*)&seT[eg * 32 + e][0];
        a0.x += s.x * w.x; a0.y += s.x * w.y; a0.z += s.x * w.z; a0.w += s.x * w.w;
        a1.x += s.y * w.x; a1.y += s.y * w.y; a1.z += s.y * w.z; a1.w += s.y * w.w;
        a2.x += s.z * w.x; a2.y += s.z * w.y; a2.z += s.z * w.z; a2.w += s.z * w.w;
        a3.x += s.w * w.x; a3.y += s.w * w.y; a3.z += s.w * w.z; a3.w += s.w * w.w;
    }
    float accs[4][4] = {{a0.x,a0.y,a0.z,a0.w},{a1.x,a1.y,a1.z,a1.w},
                        {a2.x,a2.y,a2.z,a2.w},{a3.x,a3.y,a3.z,a3.w}};
#pragma unroll
    for (int b = 0; b < 4; b++)
#pragma unroll
        for (int i = 0; i < 4; i++)
            buf[(b * 32 + cg * 4 + i) * 33 + eg] = accs[b][i];
    __syncthreads();
    if (tid < 128) {
        int b = tid >> 5, cl = tid & 31;
        float s = 0.f;
#pragma unroll 8
        for (int e = 0; e < 32; e++) s += buf[(b * 32 + cl) * 33 + e];
        int c = chunk * 32 + cl;
        float v = s + bias[c];
        if (c < DD) scaleB[(size_t)(j * 4 + b) * DD + c] = v;
        else        shiftB[(size_t)(j * 4 + b) * DD + (c - DD)] = v;
    }
}

// ---------------------------------------------------------------------------
// K2: LayerNorm + modulate, cast bf16
// ---------------------------------------------------------------------------
__global__ __launch_bounds__(256) void ln_mod_kernel(
    const float* __restrict__ x1, const float* __restrict__ x2,
    const float* __restrict__ x3, const float* __restrict__ xf,
    const float* __restrict__ scaleB, const float* __restrict__ shiftB,
    unsigned short* __restrict__ hq, unsigned short* __restrict__ hx)
{
    __shared__ float rs[4], rq[4];
    int row = blockIdx.x, tid = threadIdx.x;
    const float* src; unsigned short* dst; int sb;
    if (row < 6144) {
        int b = row / 1536, t3 = row % 1536;
        int br = t3 >> 9, t = t3 & 511;
        const float* xs = (br == 0) ? x1 : ((br == 1) ? x2 : x3);
        src = xs + ((size_t)b * TSEQ + t) * DD;
        dst = hq + (size_t)row * DD;
        sb = br * 4 + b;
    } else {
        int idx = row - 6144;
        src = xf + (size_t)idx * DD;
        dst = hx + (size_t)idx * DD;
        sb = 12 + (idx >> 9);
    }
    float4 x = ((const float4*)src)[tid];
    float s = x.x + x.y + x.z + x.w;
    float q = x.x * x.x + x.y * x.y + x.z * x.z + x.w * x.w;
    for (int o = 1; o < 64; o <<= 1) { s += __shfl_xor(s, o, 64); q += __shfl_xor(q, o, 64); }
    int lane = tid & 63, wid = tid >> 6;
    if (lane == 0) { rs[wid] = s; rq[wid] = q; }
    __syncthreads();
    float S = rs[0] + rs[1] + rs[2] + rs[3];
    float Q = rq[0] + rq[1] + rq[2] + rq[3];
    float mu = S * (1.f / DD);
    float var = Q * (1.f / DD) - mu * mu;
    float rstd = rsqrtf(var + 1e-6f);
    float4 sc = ((const float4*)(scaleB + (size_t)sb * DD))[tid];
    float4 sh = ((const float4*)(shiftB + (size_t)sb * DD))[tid];
    ushort4 o;
    o.x = f2bf((x.x - mu) * rstd * (1.f + sc.x) + sh.x);
    o.y = f2bf((x.y - mu) * rstd * (1.f + sc.y) + sh.y);
    o.z = f2bf((x.z - mu) * rstd * (1.f + sc.z) + sh.z);
    o.w = f2bf((x.w - mu) * rstd * (1.f + sc.w) + sh.w);
    ((ushort4*)dst)[tid] = o;
}

// ---------------------------------------------------------------------------
// GEMM core: 128x64 tile, BK=64, conflict-free XOR swizzle, 4 waves 2x2.
// (R2-verified best config; all later restructures were neutral or worse.)
// ---------------------------------------------------------------------------
__device__ __forceinline__ void gemm_core64(
    const unsigned short* __restrict__ A, const unsigned short* __restrict__ W,
    int m0, int n0, unsigned short* As, unsigned short* Bs,
    int tid, f32x4 acc[4][2])
{
    int lane = tid & 63, wid = tid >> 6;
    int fm = lane & 15, quad = lane >> 4;
    int wm = wid >> 1, wn = wid & 1;
    int sr = tid >> 3;                    // row 0..31
    int sc = tid & 7;                     // LDS chunk position 0..7
    int gko = (sc ^ (sr & 7)) * 8;        // global k-chunk landing at pos sc
    const unsigned short* Ap = A + (size_t)(m0 + sr) * DD + gko;
    const unsigned short* Wp = W + (size_t)(n0 + sr) * DD + gko;
    unsigned short* la = As + tid * 8;    // = sr*64 + sc*8
    unsigned short* lb = Bs + tid * 8;
    int f7 = fm & 7;
    for (int k0 = 0; k0 < DD; k0 += 64) {
#pragma unroll
        for (int i = 0; i < 4; i++)
            GLD16(Ap + (size_t)(32 * i) * DD + k0, la + i * 2048);
#pragma unroll
        for (int i = 0; i < 2; i++)
            GLD16(Wp + (size_t)(32 * i) * DD + k0, lb + i * 2048);
        __syncthreads();
#pragma unroll
        for (int kh = 0; kh < 2; kh++) {
            int sq = ((quad + 4 * kh) ^ f7) * 8;
            bf16x8 af[4], bfr[2];
#pragma unroll
            for (int mt = 0; mt < 4; mt++)
                af[mt] = *(const bf16x8*)(As + (wm * 64 + mt * 16 + fm) * 64 + sq);
#pragma unroll
            for (int nt = 0; nt < 2; nt++)
                bfr[nt] = *(const bf16x8*)(Bs + (wn * 32 + nt * 16 + fm) * 64 + sq);
#pragma unroll
            for (int mt = 0; mt < 4; mt++)
#pragma unroll
                for (int nt = 0; nt < 2; nt++)
                    acc[mt][nt] = __builtin_amdgcn_mfma_f32_16x16x32_bf16(af[mt], bfr[nt], acc[mt][nt], 0, 0, 0);
        }
        __syncthreads();
    }
}

// ---------------------------------------------------------------------------
// K3: fused Q/K/V projection -> MFMA-fragment-packed outputs.
// flat grid 1280: m-tile = id % 80 (XCD-affine), n-tile(64) = id / 80.
// ---------------------------------------------------------------------------
__global__ __launch_bounds__(256) void qkv_gemm(
    const unsigned short* __restrict__ hq, const unsigned short* __restrict__ hx,
    const unsigned short* __restrict__ qwt, const unsigned short* __restrict__ kwt,
    const unsigned short* __restrict__ vwt,
    const float* __restrict__ q_b, const float* __restrict__ k_b,
    const float* __restrict__ v_b,
    unsigned short* __restrict__ Qpk, unsigned short* __restrict__ Kpk,
    unsigned short* __restrict__ Vpk)
{
    __shared__ __align__(16) unsigned short As[128 * 64];
    __shared__ __align__(16) unsigned short Bs[64 * 64];
    int id = blockIdx.x;
    int ty = id % 80, n0 = (id / 80) * 64;
    const unsigned short *A, *W; const float* bias; int mode, m0;
    if (ty < 48) {
        m0 = ty * 128;
        int br = (m0 % 1536) >> 9;
        A = hq; W = qwt + (size_t)br * DD * DD; bias = q_b + (size_t)br * DD; mode = 0;
    } else if (ty < 64) {
        m0 = (ty - 48) * 128; A = hx; W = kwt; bias = k_b; mode = 1;
    } else {
        m0 = (ty - 64) * 128; A = hx; W = vwt; bias = v_b; mode = 2;
    }
    int tid = threadIdx.x, lane = tid & 63, wid = tid >> 6;
    int fm = lane & 15, quad = lane >> 4;
    int wm = wid >> 1, wn = wid & 1;
    f32x4 z = {0.f, 0.f, 0.f, 0.f};
    f32x4 acc[4][2];
#pragma unroll
    for (int mt = 0; mt < 4; mt++)
#pragma unroll
        for (int nt = 0; nt < 2; nt++) acc[mt][nt] = z;
    gemm_core64(A, W, m0, n0, As, Bs, tid, acc);
#pragma unroll
    for (int mt = 0; mt < 4; mt++) {
#pragma unroll
        for (int nt = 0; nt < 2; nt++) {
            int c = n0 + wn * 32 + nt * 16 + fm;
            float bv = bias[c];
            int r0 = m0 + wm * 64 + mt * 16 + quad * 4;
            int h = c >> 6;
            if (mode == 0) {
                int b = r0 / 1536, t3 = r0 % 1536;
                int kk = (c >> 5) & 1, o = c & 31;
                size_t base = ((((size_t)(b * HH + h) * 2 + kk) * 1536) + t3) * 32 + o;
#pragma unroll
                for (int reg = 0; reg < 4; reg++)
                    Qpk[base + (size_t)reg * 32] = f2bf((acc[mt][nt][reg] + bv) * 0.125f);
            } else if (mode == 1) {
                int b = r0 >> 9, n = r0 & 511;
                int kk = (c >> 5) & 1, o = c & 31;
                size_t base = ((((size_t)(b * HH + h) * 2 + kk) * 512) + n) * 32 + o;
#pragma unroll
                for (int reg = 0; reg < 4; reg++)
                    Kpk[base + (size_t)reg * 32] = f2bf(acc[mt][nt][reg] + bv);
            } else {
                int b = r0 >> 9, n = r0 & 511;
                int hd = c & 63, cv = n >> 5, ko = n & 31;
                ushort4 st;
                st.x = f2bf(acc[mt][nt][0] + bv);
                st.y = f2bf(acc[mt][nt][1] + bv);
                st.z = f2bf(acc[mt][nt][2] + bv);
                st.w = f2bf(acc[mt][nt][3] + bv);
                *(ushort4*)(Vpk + ((((size_t)(b * HH + h) * 16 + cv) * 64) + hd) * 32 + ko) = st;
            }
        }
    }
}

// ---------------------------------------------------------------------------
// K5: out projection, fp32 out remapped branch-major. flat grid 768:
// m = id % 48 (XCD-affine), n-tile(64) = id / 48.
// ---------------------------------------------------------------------------
__global__ __launch_bounds__(256) void out_gemm(
    const unsigned short* __restrict__ Ain, const unsigned short* __restrict__ owt,
    const float* __restrict__ out_b, float* __restrict__ outp)
{
    __shared__ __align__(16) unsigned short As[128 * 64];
    __shared__ __align__(16) unsigned short Bs[64 * 64];
    int id = blockIdx.x;
    int m0 = (id % 48) * 128, n0 = (id / 48) * 64;
    int br = (m0 % 1536) >> 9;
    const unsigned short* W = owt + (size_t)br * DD * DD;
    const float* bias = out_b + (size_t)br * DD;
    int tid = threadIdx.x, lane = tid & 63, wid = tid >> 6;
    int fm = lane & 15, quad = lane >> 4;
    int wm = wid >> 1, wn = wid & 1;
    f32x4 z = {0.f, 0.f, 0.f, 0.f};
    f32x4 acc[4][2];
#pragma unroll
    for (int mt = 0; mt < 4; mt++)
#pragma unroll
        for (int nt = 0; nt < 2; nt++) acc[mt][nt] = z;
    gemm_core64(Ain, W, m0, n0, As, Bs, tid, acc);
#pragma unroll
    for (int mt = 0; mt < 4; mt++) {
#pragma unroll
        for (int nt = 0; nt < 2; nt++) {
            int c = n0 + wn * 32 + nt * 16 + fm;
            float bv = bias[c];
            int r0 = m0 + wm * 64 + mt * 16 + quad * 4;
            int b = r0 / 1536, t3 = r0 % 1536, t = t3 & 511;
#pragma unroll
            for (int reg = 0; reg < 4; reg++)
                outp[(size_t)br * (BB * TSEQ * DD) + (size_t)b * (TSEQ * DD)
                     + (size_t)(t + reg) * DD + c] = acc[mt][nt][reg] + bv;
        }
    }
}

// ---------------------------------------------------------------------------
// K4: attention, 48 queries/block (R9-verified best: 255.8us). Blocks/head 32;
// per-XCD 8 consecutive heads x 32 m-tiles = 256 blocks, bijective swizzle.
// LDS 50.7KB -> 3 blocks/CU, 12 waves. T14 V-prefetch retained.
// ---------------------------------------------------------------------------
__global__ __launch_bounds__(256, 3) void attn_kernel(
    const unsigned short* __restrict__ Qpk,
    const unsigned short* __restrict__ Kpk,
    const unsigned short* __restrict__ Vpk,
    const unsigned char* __restrict__ mask,
    unsigned short* __restrict__ attn)
{
    __shared__ __align__(16) unsigned short P[48 * 520];
    __shared__ float redsum[4 * 48];
    // bijective XCD swizzle: 2048 blocks, 8 XCDs, 256 per XCD
    int orig = blockIdx.x;
    int wg = (orig & 7) * 256 + (orig >> 3);
    int bh = wg / 32, b = bh >> 4, h = bh & 15;
    int m0 = (wg % 32) * 48;
    int tid = threadIdx.x, lane = tid & 63, w = tid >> 6;
    int fm = lane & 15, quad = lane >> 4;

    const unsigned char* mp = mask + (size_t)b * NSEQ + w * 128;
    unsigned long long mw0 = __ballot(mp[lane] != 0);
    unsigned long long mw1 = __ballot(mp[64 + lane] != 0);

    // phase 1: S^T = K (Q/8)^T for 48 queries, mask as C-init
    f32x4 acc[8][3];
#pragma unroll
    for (int mt = 0; mt < 8; mt++) {
        unsigned long long word = (mt >= 4) ? mw1 : mw0;
        int kb = (mt * 16 + quad * 4) & 63;
        f32x4 ini;
#pragma unroll
        for (int reg = 0; reg < 4; reg++)
            ini[reg] = ((word >> (kb + reg)) & 1ull) ? -1e30f : 0.f;
        acc[mt][0] = ini; acc[mt][1] = ini; acc[mt][2] = ini;
    }
    const unsigned short* Kbase = Kpk + (size_t)bh * 2 * 512 * 32 + quad * 8;
    const unsigned short* Qbase = Qpk + (size_t)bh * 2 * 1536 * 32 + quad * 8;
    const unsigned short* Vbase = Vpk + (size_t)bh * 16 * 64 * 32 + (size_t)(w * 16 + fm) * 32 + quad * 8;
#pragma unroll
    for (int kk = 0; kk < 2; kk++) {
        bf16x8 bq0 = *(const bf16x8*)(Qbase + (size_t)(kk * 1536 + m0 + fm) * 32);
        bf16x8 bq1 = *(const bf16x8*)(Qbase + (size_t)(kk * 1536 + m0 + 16 + fm) * 32);
        bf16x8 bq2 = *(const bf16x8*)(Qbase + (size_t)(kk * 1536 + m0 + 32 + fm) * 32);
#pragma unroll
        for (int mt = 0; mt < 8; mt++) {
            bf16x8 ak = *(const bf16x8*)(Kbase + (size_t)(kk * 512 + w * 128 + mt * 16 + fm) * 32);
            acc[mt][0] = __builtin_amdgcn_mfma_f32_16x16x32_bf16(ak, bq0, acc[mt][0], 0, 0, 0);
            acc[mt][1] = __builtin_amdgcn_mfma_f32_16x16x32_bf16(ak, bq1, acc[mt][1], 0, 0, 0);
            acc[mt][2] = __builtin_amdgcn_mfma_f32_16x16x32_bf16(ak, bq2, acc[mt][2], 0, 0, 0);
        }
    }

    // V prefetch, first half: overlaps with exp/pack/barrier below (T14)
    bf16x8 vpre[8];
#pragma unroll
    for (int kk = 0; kk < 8; kk++)
        vpre[kk] = *(const bf16x8*)(Vbase + (size_t)kk * 64 * 32);

    // phase 2: e = exp(s), pack bf16 to LDS, column sums per q-group
    float s0 = 0.f, s1 = 0.f, s2 = 0.f;
#pragma unroll
    for (int mt = 0; mt < 8; mt++) {
        int kb = w * 128 + mt * 16 + quad * 4;
        float e00 = __expf(acc[mt][0][0]);
        float e01 = __expf(acc[mt][0][1]);
        float e02 = __expf(acc[mt][0][2]);
        float e03 = __expf(acc[mt][0][3]);
        s0 += (e00 + e01) + (e02 + e03);
        uint2 p0; p0.x = pkbf(e00, e01); p0.y = pkbf(e02, e03);
        *(uint2*)(P + (size_t)fm * 520 + kb) = p0;
        float e10 = __expf(acc[mt][1][0]);
        float e11 = __expf(acc[mt][1][1]);
        float e12 = __expf(acc[mt][1][2]);
        float e13 = __expf(acc[mt][1][3]);
        s1 += (e10 + e11) + (e12 + e13);
        uint2 p1; p1.x = pkbf(e10, e11); p1.y = pkbf(e12, e13);
        *(uint2*)(P + (size_t)(16 + fm) * 520 + kb) = p1;
        float e20 = __expf(acc[mt][2][0]);
        float e21 = __expf(acc[mt][2][1]);
        float e22 = __expf(acc[mt][2][2]);
        float e23 = __expf(acc[mt][2][3]);
        s2 += (e20 + e21) + (e22 + e23);
        uint2 p2; p2.x = pkbf(e20, e21); p2.y = pkbf(e22, e23);
        *(uint2*)(P + (size_t)(32 + fm) * 520 + kb) = p2;
    }
    s0 += __shfl_xor(s0, 16, 64); s0 += __shfl_xor(s0, 32, 64);
    s1 += __shfl_xor(s1, 16, 64); s1 += __shfl_xor(s1, 32, 64);
    s2 += __shfl_xor(s2, 16, 64); s2 += __shfl_xor(s2, 32, 64);
    if (quad == 0) {
        redsum[w * 48 + fm] = s0;
        redsum[w * 48 + 16 + fm] = s1;
        redsum[w * 48 + 32 + fm] = s2;
    }
    __syncthreads();

    // phase 3: O^T = V^T P; second-half V loads issued first, then MFMA loop
    float inv0 = 1.f / (redsum[fm] + redsum[48 + fm] + redsum[96 + fm] + redsum[144 + fm]);
    float inv1 = 1.f / (redsum[16 + fm] + redsum[64 + fm] + redsum[112 + fm] + redsum[160 + fm]);
    float inv2 = 1.f / (redsum[32 + fm] + redsum[80 + fm] + redsum[128 + fm] + redsum[176 + fm]);
    bf16x8 vrest[8];
#pragma unroll
    for (int kk = 0; kk < 8; kk++)
        vrest[kk] = *(const bf16x8*)(Vbase + (size_t)(8 + kk) * 64 * 32);
    f32x4 z = {0.f, 0.f, 0.f, 0.f};
    f32x4 o0 = z, o1 = z, o2 = z;
    const unsigned short* Pp0 = P + (size_t)fm * 520 + quad * 8;
    const unsigned short* Pp1 = P + (size_t)(16 + fm) * 520 + quad * 8;
    const unsigned short* Pp2 = P + (size_t)(32 + fm) * 520 + quad * 8;
#pragma unroll
    for (int kk = 0; kk < 8; kk++) {
        bf16x8 p0 = *(const bf16x8*)(Pp0 + kk * 32);
        bf16x8 p1 = *(const bf16x8*)(Pp1 + kk * 32);
        bf16x8 p2 = *(const bf16x8*)(Pp2 + kk * 32);
        o0 = __builtin_amdgcn_mfma_f32_16x16x32_bf16(vpre[kk], p0, o0, 0, 0, 0);
        o1 = __builtin_amdgcn_mfma_f32_16x16x32_bf16(vpre[kk], p1, o1, 0, 0, 0);
        o2 = __builtin_amdgcn_mfma_f32_16x16x32_bf16(vpre[kk], p2, o2, 0, 0, 0);
    }
#pragma unroll
    for (int kk = 0; kk < 8; kk++) {
        bf16x8 p0 = *(const bf16x8*)(Pp0 + (8 + kk) * 32);
        bf16x8 p1 = *(const bf16x8*)(Pp1 + (8 + kk) * 32);
        bf16x8 p2 = *(const bf16x8*)(Pp2 + (8 + kk) * 32);
        o0 = __builtin_amdgcn_mfma_f32_16x16x32_bf16(vrest[kk], p0, o0, 0, 0, 0);
        o1 = __builtin_amdgcn_mfma_f32_16x16x32_bf16(vrest[kk], p1, o1, 0, 0, 0);
        o2 = __builtin_amdgcn_mfma_f32_16x16x32_bf16(vrest[kk], p2, o2, 0, 0, 0);
    }
    ushort4 r0, r1, r2;
    r0.x = f2bf(o0[0] * inv0); r0.y = f2bf(o0[1] * inv0);
    r0.z = f2bf(o0[2] * inv0); r0.w = f2bf(o0[3] * inv0);
    r1.x = f2bf(o1[0] * inv1); r1.y = f2bf(o1[1] * inv1);
    r1.z = f2bf(o1[2] * inv1); r1.w = f2bf(o1[3] * inv1);
    r2.x = f2bf(o2[0] * inv2); r2.y = f2bf(o2[1] * inv2);
    r2.z = f2bf(o2[2] * inv2); r2.w = f2bf(o2[3] * inv2);
    size_t col = h * HD + w * 16 + quad * 4;
    *(ushort4*)(attn + ((size_t)(b * 1536 + m0 + fm)) * DD + col) = r0;
    *(ushort4*)(attn + ((size_t)(b * 1536 + m0 + 16 + fm)) * DD + col) = r1;
    *(ushort4*)(attn + ((size_t)(b * 1536 + m0 + 32 + fm)) * DD + col) = r2;
}

// ---------------------------------------------------------------------------
extern "C" void kernel_launch(void* const* d_in, const int* in_sizes, int n_in,
                              void* d_out, int out_size, void* d_ws, size_t ws_size,
                              hipStream_t stream)
{
    const float* x1   = (const float*)d_in[0];
    const float* x2   = (const float*)d_in[1];
    const float* x3   = (const float*)d_in[2];
    const float* xf   = (const float*)d_in[3];
    const float* emb  = (const float*)d_in[4];
    const unsigned char* mask = (const unsigned char*)d_in[5];
    const float* adaln_w = (const float*)d_in[6];
    const float* adaln_b = (const float*)d_in[7];
    const float* xf_w = (const float*)d_in[8];
    const float* xf_b = (const float*)d_in[9];
    const float* q_w  = (const float*)d_in[10];
    const float* q_b  = (const float*)d_in[11];
    const float* k_w  = (const float*)d_in[12];
    const float* k_b  = (const float*)d_in[13];
    const float* v_w  = (const float*)d_in[14];
    const float* v_b  = (const float*)d_in[15];
    const float* out_w = (const float*)d_in[16];
    const float* out_b = (const float*)d_in[17];

    char* ws = (char*)d_ws;
    float* scaleB        = (float*)(ws + 0);
    float* shiftB        = (float*)(ws + 65536);
    unsigned short* hq   = (unsigned short*)(ws + 131072);     // 12.58 MB (reused for attn out)
    unsigned short* hx   = (unsigned short*)(ws + 12713984);   // 4.19 MB
    unsigned short* Qpk  = (unsigned short*)(ws + 16908288);   // 12.58 MB
    unsigned short* Kpk  = (unsigned short*)(ws + 29491200);   // 4.19 MB
    unsigned short* Vpk  = (unsigned short*)(ws + 33685504);   // 4.19 MB
    unsigned short* qwt  = (unsigned short*)(ws + 37879808);   // 6.29 MB
    unsigned short* kwt  = (unsigned short*)(ws + 44171264);   // 2.10 MB
    unsigned short* vwt  = (unsigned short*)(ws + 46268416);   // 2.10 MB
    unsigned short* owt  = (unsigned short*)(ws + 48365568);   // 6.29 MB (end ~54.7 MB)

    tw_all_kernel<<<dim3(16, 16, 8), 256, 0, stream>>>(q_w, k_w, v_w, out_w,
                                                       qwt, kwt, vwt, owt);
    adaln_kernel<<<dim3(64, 4), 256, 0, stream>>>(emb, adaln_w, adaln_b, xf_w, xf_b,
                                                  scaleB, shiftB);
    ln_mod_kernel<<<8192, 256, 0, stream>>>(x1, x2, x3, xf, scaleB, shiftB, hq, hx);
    qkv_gemm<<<1280, 256, 0, stream>>>(hq, hx, qwt, kwt, vwt, q_b, k_b, v_b,
                                       Qpk, Kpk, Vpk);
    attn_kernel<<<2048, 256, 0, stream>>>(Qpk, Kpk, Vpk, mask, hq);
    out_gemm<<<768, 256, 0, stream>>>(hq, owt, out_b, (float*)d_out);
}